// Round 9
// baseline (261.735 us; speedup 1.0000x reference)
//
#include <hip/hip_runtime.h>

// PlanePriorNet: P=256 patches x PT=64 pts, D=768. float32 I/O.
// Round 17: (A) point_mlp6 stage 2 weights staged through LDS: 8 k-rows
// (4KB) double-buffered, coop float2 loads (coalesced) + ds_write, one
// barrier per 8-k step; per-wave redundant global loads (the last
// untested stall mechanism after R10-R16) are gone. w bit value, FMA
// statement form and k-order 0..255 unchanged => bit-identical h2/ppd
// => identical top-k. (B) plane_k fused into final_mlp_mfma stage 5
// (rotL already in LDS); rotw buffer + one launch removed; identical
// per-element expressions => bit-identical out_plane.

#define P 256
#define PT 64
#define NPTS 16384          // P*PT
#define M2N 32768           // 2*N
#define D 768
#define SENTK 0xFFFFFFFFFFFFFFFFull

typedef __attribute__((ext_vector_type(8))) short bfrag;   // 8 x bf16 (4 VGPR)
typedef __attribute__((ext_vector_type(4))) float ffrag;   // 4 x f32 acc

#define MFMA16(a, b, c) __builtin_amdgcn_mfma_f32_16x16x32_bf16((a), (b), (c), 0, 0, 0)

// round-to-nearest-even fp32 -> bf16
__device__ __forceinline__ ushort f2bf(float x) {
  unsigned u = __float_as_uint(x);
  u = (u + 0x7FFFu + ((u >> 16) & 1u)) >> 16;
  return (ushort)u;
}
__device__ __forceinline__ float bf2f(ushort u) {
  return __uint_as_float((unsigned)u << 16);
}

// ---------------------------------------------------------------- kernel A
// Split by column chunk: chunk 0 -> A1d (fp64, 256 cols); chunks 1,2 -> B1 (fp32).
__global__ __launch_bounds__(256) void patch_pre2(
    const float* __restrict__ lf, const float* __restrict__ sw1,
    const float* __restrict__ sb1, const float* __restrict__ mw1,
    const float* __restrict__ mb1, double* __restrict__ A1d, float* __restrict__ B1) {
  __shared__ float lfs[768];
  const int b = blockIdx.x, t = threadIdx.x;
  const int p = b / 3, chunk = b % 3;
  for (int i = t; i < 768; i += 256) lfs[i] = lf[p * 768 + i];
  __syncthreads();
  if (chunk == 0) {
    double a = (double)sb1[t];
    for (int d = 0; d < 768; ++d)
      a += (double)lfs[d] * (double)sw1[d * 256 + t];
    A1d[p * 256 + t] = a;
  } else {
    const int c = (chunk - 1) * 256 + t;
    float bb = 0.f;
    for (int d = 0; d < 768; ++d)
      bb += lfs[d] * mw1[d * 512 + c];
    B1[p * 512 + c] = mb1[c] + bb;
  }
}

// ---------------------------------------------------------------- kernel B
// Point MLP, fp64, half-patch blocks (32 pts, 512 blocks x 512 thr).
// h1T [256][34] doubles (pitch 34, 69632 B); h2s [32][129] overlays h1T.
// Stage 1: thread t -> k=t&255, rows (t>>8)*16..+16 (same per-elem expr).
// Stage 2: thread t -> col c=t&127, pt-group ptq=t>>7 (8 pts), 8 accs;
//   weights staged via LDS bufW[2][1024]: per 8-k step, coop float2 load
//   (coalesced 4KB) + ds_write next tile, compute current, 1 barrier.
__global__ __launch_bounds__(512, 4) void point_mlp6(
    const float* __restrict__ pos, const float* __restrict__ sw1,
    const float* __restrict__ sw2, const float* __restrict__ sb2,
    const float* __restrict__ sw3, const float* __restrict__ sb3,
    const double* __restrict__ A1d, double* __restrict__ ppd, float* __restrict__ ppf) {
  __shared__ double smemD[8704];   // h1T [k][pt] pitch 34 (69632 B); h2s overlay
  __shared__ double posd[96];
  __shared__ __align__(16) float bufW[2][1024];   // 2 x 8 k-rows x 128 c
  double* h1T = smemD;
  double* h2s = smemD;

  const int b = blockIdx.x, t = threadIdx.x;
  const int p = b >> 1, qb = b & 1;    // pts [qb*32, qb*32+32)
  if (t < 96) posd[t] = (double)pos[p * 192 + qb * 96 + t];
  __syncthreads();

  // stage 1: h1T[k][r] = relu(A1[k] + pos . sw1'[k])   (round-4 expression)
  {
    const int k = t & 255, rb = (t >> 8) * 16;
    const double a1 = A1d[p * 256 + k];
    const double w0 = (double)sw1[768 * 256 + k];
    const double w1 = (double)sw1[769 * 256 + k];
    const double w2 = (double)sw1[770 * 256 + k];
    for (int r = rb; r < rb + 16; ++r) {
      const double* pp = &posd[r * 3];
      const double v = a1 + pp[0] * w0 + pp[1] * w1 + pp[2] * w2;
      h1T[k * 34 + r] = v > 0.0 ? v : 0.0;
    }
  }
  // prologue: stage k-rows 0..7 into bufW[0] (barrier below covers h1T too)
  *(float2*)&bufW[0][t * 2] = *(const float2*)&sw2[t * 2];
  __syncthreads();

  // stage 2: h2[pt][c] = relu(sb2 + sum_k h1[pt][k]*sw2[k][c])
  // (per-acc k-chain sequential 0..255, identical statement form => bit-identical)
  {
    const int c = t & 127, ptq = t >> 7;   // pts ptq*8 .. ptq*8+7
    double acc[8];
    #pragma unroll
    for (int i = 0; i < 8; ++i) acc[i] = 0.0;
    const double* hp = h1T + ptq * 8;      // hp[k*34 + i], 16B-aligned
    #pragma unroll 1
    for (int kt = 0; kt < 32; ++kt) {
      const int cur = kt & 1;
      if (kt < 31) {                        // prefetch next 8 rows -> other buf
        const float2 v = *(const float2*)&sw2[(kt + 1) * 1024 + t * 2];
        *(float2*)&bufW[cur ^ 1][t * 2] = v;
      }
      #pragma unroll
      for (int kk = 0; kk < 8; ++kk) {
        const int k = kt * 8 + kk;
        const double2 h01 = *(const double2*)&hp[k * 34];
        const double2 h23 = *(const double2*)&hp[k * 34 + 2];
        const double2 h45 = *(const double2*)&hp[k * 34 + 4];
        const double2 h67 = *(const double2*)&hp[k * 34 + 6];
        const double w = (double)bufW[cur][kk * 128 + c];
        acc[0] += h01.x * w;
        acc[1] += h01.y * w;
        acc[2] += h23.x * w;
        acc[3] += h23.y * w;
        acc[4] += h45.x * w;
        acc[5] += h45.y * w;
        acc[6] += h67.x * w;
        acc[7] += h67.y * w;
      }
      __syncthreads();   // next tile written; all reads of this step done
    }
    // last barrier above also guarantees all h1T reads finished -> overlay h2s
    #pragma unroll
    for (int i = 0; i < 8; ++i) {
      const int pt = ptq * 8 + i;
      const double u = acc[i] + (double)sb2[c];
      h2s[pt * 129 + c] = u > 0.0 ? u : 0.0;
    }
  }
  __syncthreads();

  // stage 3: h3 + tanh + writes (96 threads; round-4 sequential c-sum)
  if (t < 96) {
    const int r = t / 3, j = t % 3;
    double u = (double)sb3[j];
    #pragma unroll 4
    for (int c = 0; c < 128; ++c)
      u += h2s[r * 129 + c] * (double)sw3[c * 3 + j];
    u = u > 0.0 ? u : 0.0;
    const int s = qb * 32 + r;
    const double po = posd[r * 3 + j];
    const double np_ = tanh(u) + po;
    const size_t rn = (size_t)(p * 128 + 64 + s) * 3 + j;
    const size_t ro = (size_t)(p * 128 + s) * 3 + j;
    ppd[rn] = np_;  ppf[rn] = (float)np_;
    ppd[ro] = po;   ppf[ro] = (float)po;
  }
}

// ---------------------------------------------------------------- kernel C
// Top-9 via u64 keys: key=(bits(d2)&~127)|j; branch-free sorted-insert;
// 4 segments x 32 candidates per row; tree merge via LDS (9+9 inserts).
__device__ __forceinline__ void ins9(unsigned long long* s, unsigned long long key) {
  #pragma unroll
  for (int k = 8; k >= 1; --k) {
    const unsigned long long lo = s[k - 1];
    const unsigned long long mx = key > lo ? key : lo;
    s[k] = (key >= s[k]) ? s[k] : mx;
  }
  s[0] = key < s[0] ? key : s[0];
}

__global__ __launch_bounds__(512) void neighbors_k2(const double* __restrict__ ppd,
                                                    int* __restrict__ nbr) {
  __shared__ double PX[128], PY[128], PZ[128];
  __shared__ unsigned long long mbuf[2][128][9];   // 18432 B
  const int p = blockIdx.x, t = threadIdx.x;
  const int row = t & 127, seg = t >> 7;
  if (t < 128) {
    PX[t] = ppd[(p * 128 + t) * 3 + 0];
    PY[t] = ppd[(p * 128 + t) * 3 + 1];
    PZ[t] = ppd[(p * 128 + t) * 3 + 2];
  }
  __syncthreads();
  const double R2d = 0.3 * 0.3;
  const double xi = PX[row], yi = PY[row], zi = PZ[row];
  unsigned long long s[9];
  #pragma unroll
  for (int k = 0; k < 9; ++k) s[k] = SENTK;
  const int j0 = seg * 32;
  for (int jj = 0; jj < 32; ++jj) {
    const int j = j0 + jj;
    const double dx = PX[j] - xi, dy = PY[j] - yi, dz = PZ[j] - zi;
    const double d2 = dx * dx + dy * dy + dz * dz;
    unsigned long long key =
        (((unsigned long long)__double_as_longlong(d2)) & ~127ull) | (unsigned long long)j;
    key = (d2 <= R2d) ? key : SENTK;
    ins9(s, key);
  }
  if (seg & 1) {
    #pragma unroll
    for (int k = 0; k < 9; ++k) mbuf[seg >> 1][row][k] = s[k];
  }
  __syncthreads();
  if (!(seg & 1)) {
    #pragma unroll
    for (int m = 0; m < 9; ++m) ins9(s, mbuf[seg >> 1][row][m]);
  }
  if (seg == 2) {
    #pragma unroll
    for (int k = 0; k < 9; ++k) mbuf[1][row][k] = s[k];
  }
  __syncthreads();
  if (seg == 0) {
    #pragma unroll
    for (int m = 0; m < 9; ++m) ins9(s, mbuf[1][row][m]);
    #pragma unroll
    for (int k = 0; k < 9; ++k)
      nbr[(p * 128 + row) * 9 + k] = (s[k] == SENTK) ? -1 : (int)(s[k] & 127);
  }
}

// ---------------------------------------------------------------- kernel W
// Pack mw1[768:896], mw2, mw3(pad N->16), cw2(hi/lo) into MFMA B-fragment order:
// dst[((nt*KT + kt)*64 + lane)*8 + j] = W[kt*32 + (lane>>4)*8 + j][nt*16 + (lane&15)]
__global__ __launch_bounds__(256) void prepack_w(
    const float* __restrict__ mw1, const float* __restrict__ mw2,
    const float* __restrict__ mw3, const float* __restrict__ cw2,
    ushort* __restrict__ W1p, ushort* __restrict__ W2p, ushort* __restrict__ W3p,
    ushort* __restrict__ C2h, ushort* __restrict__ C2l) {
  const int idx = blockIdx.x * 256 + threadIdx.x;
  if (idx < 65536) {                       // W1p: K=128 (kt<4), N=512 (nt<32)
    const int j = idx & 7, l = (idx >> 3) & 63, kt = (idx >> 9) & 3, nt = idx >> 11;
    const int k = kt * 32 + (l >> 4) * 8 + j, n = nt * 16 + (l & 15);
    W1p[idx] = f2bf(mw1[(768 + k) * 512 + n]);
  } else if (idx < 196608) {               // W2p: K=512 (kt<16), N=256 (nt<16)
    const int q = idx - 65536;
    const int j = q & 7, l = (q >> 3) & 63, kt = (q >> 9) & 15, nt = q >> 13;
    const int k = kt * 32 + (l >> 4) * 8 + j, n = nt * 16 + (l & 15);
    W2p[q] = f2bf(mw2[k * 256 + n]);
  } else if (idx < 200704) {               // W3p: K=256 (kt<8), N=9 padded to 16
    const int q = idx - 196608;
    const int j = q & 7, l = (q >> 3) & 63, kt = q >> 9;
    const int k = kt * 32 + (l >> 4) * 8 + j, n = l & 15;
    W3p[q] = (n < 9) ? f2bf(mw3[k * 9 + n]) : (ushort)0;
  } else if (idx < 208896) {               // C2h/C2l: K=64 (kt<2), N=128 (nt<8)
    const int q = idx - 200704;
    const int j = q & 7, l = (q >> 3) & 63, kt = (q >> 9) & 1, nt = q >> 10;
    const int k = kt * 32 + (l >> 4) * 8 + j, n = nt * 16 + (l & 15);
    const float v = cw2[k * 128 + n];
    const ushort hi = f2bf(v);
    C2h[q] = hi;
    C2l[q] = f2bf(v - bf2f(hi));
  }
}

// ---------------------------------------------------------------- kernel D
// Edge MLP via MFMA: 16 pts/block (144 edges, M-tiles=9), N=128, K=64.
// 512 threads (8 waves); wave w owns the single 16-col N-tile nt=w.
#define EPITCH 80    // m1 pitch (ushorts): 160 B rows
#define M2PITCH 132  // m2 pitch (ushorts): 264 B rows
__global__ __launch_bounds__(512, 6) void edge_mfma(
    const float* __restrict__ ppf, const int* __restrict__ nbr,
    const float* __restrict__ cw1, const float* __restrict__ cb1,
    const ushort* __restrict__ C2h, const ushort* __restrict__ C2l,
    const float* __restrict__ cb2, ushort* __restrict__ aggB) {
  __shared__ float posL[128 * 3];
  __shared__ int nbrL[144];
  __shared__ __align__(16) ushort buf[2 * 144 * EPITCH];  // m1h|m1l, reused as m2
  ushort* m1h = buf;
  ushort* m1l = buf + 144 * EPITCH;
  ushort* m2L = buf;   // 144*132 = 19008 <= 23040

  const int b = blockIdx.x, t = threadIdx.x;
  const int p = b >> 3, off = (b & 7) * 16;
  for (int i = t; i < 384; i += 512) posL[i] = ppf[p * 384 + i];
  if (t < 144) nbrL[t] = nbr[(p * 128 + off) * 9 + t];
  __syncthreads();

  // phase 1: m1[e][c] = relu(feat . cw1[:,c] + cb1[c]) -> bf16 hi/lo
  // thread t -> channel pair (c0,c0+1), edge group eg (9 edges each)
  {
    const int c0 = (t & 31) * 2, eg = t >> 5;
    float w1a[6], w1b[6];
    #pragma unroll
    for (int q = 0; q < 6; ++q) {
      w1a[q] = cw1[q * 64 + c0];
      w1b[q] = cw1[q * 64 + c0 + 1];
    }
    const float b1a = cb1[c0], b1b = cb1[c0 + 1];
    for (int e = eg; e < 144; e += 16) {
      const int pl = e / 9;
      const int j = nbrL[e];
      const int jj = j < 0 ? 0 : j;
      const int ctr = off + pl;
      const float nx = posL[jj * 3], ny = posL[jj * 3 + 1], nz = posL[jj * 3 + 2];
      const float cx = posL[ctr * 3], cy = posL[ctr * 3 + 1], cz = posL[ctr * 3 + 2];
      float va = b1a + nx * w1a[0] + ny * w1a[1] + nz * w1a[2] +
                 (nx - cx) * w1a[3] + (ny - cy) * w1a[4] + (nz - cz) * w1a[5];
      va = fmaxf(va, 0.f);
      float vb = b1b + nx * w1b[0] + ny * w1b[1] + nz * w1b[2] +
                 (nx - cx) * w1b[3] + (ny - cy) * w1b[4] + (nz - cz) * w1b[5];
      vb = fmaxf(vb, 0.f);
      const ushort hia = f2bf(va), hib = f2bf(vb);
      const ushort loa = f2bf(va - bf2f(hia)), lob = f2bf(vb - bf2f(hib));
      *(unsigned*)&m1h[e * EPITCH + c0] = (unsigned)hia | ((unsigned)hib << 16);
      *(unsigned*)&m1l[e * EPITCH + c0] = (unsigned)loa | ((unsigned)lob << 16);
    }
  }
  __syncthreads();

  // phase 2: MFMA, wave w covers cols [w*16, w*16+16)
  const int w = t >> 6, l = t & 63, lrow = l & 15, quad = l >> 4;
  ffrag acc[9];
  {
    bfrag Bh[2], Bl[2];  // [kt]
    #pragma unroll
    for (int kt = 0; kt < 2; ++kt) {
      const int bi = ((w * 2 + kt) * 64 + l) * 8;
      Bh[kt] = *(const bfrag*)&C2h[bi];
      Bl[kt] = *(const bfrag*)&C2l[bi];
    }
    #pragma unroll
    for (int mt = 0; mt < 9; ++mt) {
      bfrag Ah[2], Al[2];
      #pragma unroll
      for (int kt = 0; kt < 2; ++kt) {
        const int ai = (mt * 16 + lrow) * EPITCH + kt * 32 + quad * 8;
        Ah[kt] = *(const bfrag*)&m1h[ai];
        Al[kt] = *(const bfrag*)&m1l[ai];
      }
      ffrag a = (ffrag){0.f, 0.f, 0.f, 0.f};
      #pragma unroll
      for (int kt = 0; kt < 2; ++kt) {
        a = MFMA16(Ah[kt], Bh[kt], a);
        a = MFMA16(Ah[kt], Bl[kt], a);
        a = MFMA16(Al[kt], Bh[kt], a);
      }
      acc[mt] = a;
    }
  }
  __syncthreads();  // all m1 reads done; buf reusable

  // phase 3: epilogue bias+relu -> bf16 -> m2L
  {
    const float cbv = cb2[w * 16 + lrow];
    const int col = w * 16 + lrow;
    #pragma unroll
    for (int mt = 0; mt < 9; ++mt) {
      #pragma unroll
      for (int r = 0; r < 4; ++r) {
        const int row = mt * 16 + quad * 4 + r;
        m2L[row * M2PITCH + col] = f2bf(fmaxf(acc[mt][r] + cbv, 0.f));
      }
    }
  }
  __syncthreads();

  // phase 4: max over valid neighbors, channel pairs via b32 reads
  // (ushort compare valid: all values >= 0)
  for (int o = t; o < 1024; o += 512) {
    const int pt = o >> 6, cc = (o & 63) * 2;
    ushort b0 = 0, b1 = 0;
    #pragma unroll
    for (int s = 0; s < 9; ++s) {
      if (nbrL[pt * 9 + s] >= 0) {
        const unsigned u = *(const unsigned*)&m2L[(pt * 9 + s) * M2PITCH + cc];
        const ushort u0 = (ushort)u, u1 = (ushort)(u >> 16);
        b0 = u0 > b0 ? u0 : b0;
        b1 = u1 > b1 ? u1 : b1;
      }
    }
    *(unsigned*)&aggB[(size_t)(p * 128 + off + pt) * 128 + cc] =
        (unsigned)b0 | ((unsigned)b1 << 16);
  }
}

// ---------------------------------------------------------------- kernel E
// Final MLP via MFMA: 32 rows/block, 1024 blocks. agg bf16.
// Stage 5 (fused plane_k): plane outputs for this block's 32 rot rows.
#define PA  136   // aT pitch (bf16 elems)
#define PG1 520
#define PG2 264
__global__ __launch_bounds__(256) void final_mlp_mfma(
    const ushort* __restrict__ aggB, const float* __restrict__ B1,
    const ushort* __restrict__ W1p, const ushort* __restrict__ W2p,
    const ushort* __restrict__ W3p, const float* __restrict__ mb2,
    const float* __restrict__ mb3, const float* __restrict__ ppf,
    float* __restrict__ out_plane, float* __restrict__ out_rc) {
  __shared__ __align__(16) ushort g1T[32 * PG1];   // 33280 B
  __shared__ __align__(16) ushort reg2[32 * PG2];  // 16896 B: aT then g2T
  __shared__ float rotL[32 * 9];
  const int b = blockIdx.x, t = threadIdx.x;
  const int w = t >> 6, l = t & 63;
  const int lrow = l & 15, quad = l >> 4;
  int p, off;
  if (b < 512) { p = b >> 1;         off = (b & 1) * 32; }
  else         { p = (b - 512) >> 1; off = 64 + ((b - 512) & 1) * 32; }
  const int n0 = b * 32;

  // ---- stage 0: aggB tile (bf16) -> LDS aT[32][128] pitch PA
  {
    ushort* aT = reg2;
    const int r0 = t >> 3, sg = (t & 7) * 16;
    const ushort* src = aggB + (size_t)(p * 128 + off + r0) * 128 + sg;
    const uint4 v0 = *(const uint4*)src;
    const uint4 v1 = *(const uint4*)(src + 8);
    *(uint4*)&aT[r0 * PA + sg] = v0;
    *(uint4*)&aT[r0 * PA + sg + 8] = v1;
  }
  __syncthreads();

  // ---- stage 1: g1 (M=32, N=512, K=128); wave w: N cols [w*128, w*128+128)
  {
    const ushort* aT = reg2;
    bfrag a[2][4];
    #pragma unroll
    for (int mt = 0; mt < 2; ++mt)
      #pragma unroll
      for (int kt = 0; kt < 4; ++kt)
        a[mt][kt] = *(const bfrag*)&aT[(mt * 16 + lrow) * PA + kt * 32 + quad * 8];
    ffrag acc[2][8];
    #pragma unroll
    for (int nti = 0; nti < 8; ++nti) {
      const float bv = B1[p * 512 + (w * 8 + nti) * 16 + lrow];
      acc[0][nti] = (ffrag){bv, bv, bv, bv};
      acc[1][nti] = acc[0][nti];
    }
    #pragma unroll
    for (int nti = 0; nti < 8; ++nti) {
      const int nt = w * 8 + nti;
      #pragma unroll
      for (int kt = 0; kt < 4; ++kt) {
        const bfrag bb = *(const bfrag*)&W1p[((nt * 4 + kt) * 64 + l) * 8];
        acc[0][nti] = MFMA16(a[0][kt], bb, acc[0][nti]);
        acc[1][nti] = MFMA16(a[1][kt], bb, acc[1][nti]);
      }
    }
    #pragma unroll
    for (int mt = 0; mt < 2; ++mt)
      #pragma unroll
      for (int nti = 0; nti < 8; ++nti) {
        const int col = (w * 8 + nti) * 16 + lrow;
        #pragma unroll
        for (int r = 0; r < 4; ++r)
          g1T[(mt * 16 + quad * 4 + r) * PG1 + col] = f2bf(fmaxf(acc[mt][nti][r], 0.f));
      }
  }
  __syncthreads();

  // ---- stage 2: g2 (M=32, N=256, K=512); wave w: N cols [w*64, w*64+64)
  {
    bfrag a[2][16];
    #pragma unroll
    for (int mt = 0; mt < 2; ++mt)
      #pragma unroll
      for (int kt = 0; kt < 16; ++kt)
        a[mt][kt] = *(const bfrag*)&g1T[(mt * 16 + lrow) * PG1 + kt * 32 + quad * 8];
    ffrag acc[2][4];
    #pragma unroll
    for (int nti = 0; nti < 4; ++nti) {
      acc[0][nti] = (ffrag){0.f, 0.f, 0.f, 0.f};
      acc[1][nti] = acc[0][nti];
    }
    #pragma unroll
    for (int nti = 0; nti < 4; ++nti) {
      const int nt = w * 4 + nti;
      #pragma unroll
      for (int kt = 0; kt < 16; ++kt) {
        const bfrag bb = *(const bfrag*)&W2p[((nt * 16 + kt) * 64 + l) * 8];
        acc[0][nti] = MFMA16(a[0][kt], bb, acc[0][nti]);
        acc[1][nti] = MFMA16(a[1][kt], bb, acc[1][nti]);
      }
    }
    ushort* g2T = reg2;
    #pragma unroll
    for (int mt = 0; mt < 2; ++mt)
      #pragma unroll
      for (int nti = 0; nti < 4; ++nti) {
        const int col = (w * 4 + nti) * 16 + lrow;
        const float bv = mb2[col];
        #pragma unroll
        for (int r = 0; r < 4; ++r)
          g2T[(mt * 16 + quad * 4 + r) * PG2 + col] =
              f2bf(fmaxf(acc[mt][nti][r] + bv, 0.f));
      }
  }
  __syncthreads();

  // ---- stage 3: g3 (M=32, N=16 padded, K=256); waves 0,1 take mt=w
  if (w < 2) {
    const ushort* g2T = reg2;
    ffrag acc = (ffrag){0.f, 0.f, 0.f, 0.f};
    #pragma unroll
    for (int kt = 0; kt < 8; ++kt) {
      const bfrag aa = *(const bfrag*)&g2T[(w * 16 + lrow) * PG2 + kt * 32 + quad * 8];
      const bfrag bb = *(const bfrag*)&W3p[(kt * 64 + l) * 8];
      acc = MFMA16(aa, bb, acc);
    }
    if (lrow < 9) {
      const float bv = mb3[lrow];
      #pragma unroll
      for (int r = 0; r < 4; ++r) {
        const int m = w * 16 + quad * 4 + r;
        rotL[m * 9 + lrow] = fmaxf(acc[r] + bv, 0.f);
      }
    }
  }
  __syncthreads();

  // ---- stage 4: rot_constrain
  for (int idx = t; idx < 288; idx += 256) {
    const int r = idx / 9, e = idx % 9, ii = e / 3, jj = e % 3;
    const float* R = &rotL[r * 9];
    out_rc[(size_t)(n0 + r) * 9 + e] =
        R[ii] * R[jj] + R[3 + ii] * R[3 + jj] + R[6 + ii] * R[6 + jj];
  }

  // ---- stage 5: plane outputs for q in [n0*16, n0*16+512)  (fused plane_k)
  for (int ii = t; ii < 512; ii += 256) {
    const int q = n0 * 16 + ii;
    const int n_loc = ii >> 4, tt = ii & 15;
    const float* R = &rotL[n_loc * 9];
    const int tx = tt & 3, ty = tt >> 2;
    const double step = 0.4 / 3.0;
    const float X = (tx == 3) ? 0.2f : (float)((double)tx * step - 0.2);
    const float Y = (ty == 3) ? 0.2f : (float)((double)ty * step - 0.2);
    const int m = q & (M2N - 1);
    int pp, s;
    if (m < NPTS) { pp = m >> 6; s = m & 63; }
    else          { const int mm = m - NPTS; pp = mm >> 6; s = 64 + (mm & 63); }
    const float* C = &ppf[(pp * 128 + s) * 3];
    #pragma unroll
    for (int i2 = 0; i2 < 3; ++i2) {
      const float d = R[i2 * 3 + 0] * X + R[i2 * 3 + 1] * Y;  // npts z == 0
      out_plane[(size_t)q * 3 + i2] = d + C[i2];
    }
  }
}

// ---------------------------------------------------------------- launch
extern "C" void kernel_launch(void* const* d_in, const int* in_sizes, int n_in,
                              void* d_out, int out_size, void* d_ws, size_t ws_size,
                              hipStream_t stream) {
  const float* pos       = (const float*)d_in[1];
  const float* local_fea = (const float*)d_in[4];
  const float* sw1 = (const float*)d_in[5];
  const float* sb1 = (const float*)d_in[6];
  const float* sw2 = (const float*)d_in[7];
  const float* sb2 = (const float*)d_in[8];
  const float* sw3 = (const float*)d_in[9];
  const float* sb3 = (const float*)d_in[10];
  const float* cw1 = (const float*)d_in[11];
  const float* cb1 = (const float*)d_in[12];
  const float* cw2 = (const float*)d_in[13];
  const float* cb2 = (const float*)d_in[14];
  const float* mw1 = (const float*)d_in[15];
  const float* mb1 = (const float*)d_in[16];
  const float* mw2 = (const float*)d_in[17];
  const float* mb2 = (const float*)d_in[18];
  const float* mw3 = (const float*)d_in[19];
  const float* mb3 = (const float*)d_in[20];

  char* ws = (char*)d_ws;
  double* A1d  = (double*)(ws + 0);         // 524288
  double* ppd  = (double*)(ws + 524288);    // 786432
  float*  B1   = (float*)(ws + 1310720);    // 524288
  float*  ppf  = (float*)(ws + 1835008);    // 393216
  int*    nbr  = (int*)(ws + 2228224);      // 1179648
  ushort* aggB = (ushort*)(ws + 3407872);   // 8388608
  ushort* W1p  = (ushort*)(ws + 12976128);  // 131072
  ushort* W2p  = (ushort*)(ws + 13107200);  // 262144
  ushort* W3p  = (ushort*)(ws + 13369344);  // 8192
  ushort* C2h  = (ushort*)(ws + 13377536);  // 16384
  ushort* C2l  = (ushort*)(ws + 13393920);  // 16384 (end 13410304)

  float* out_plane = (float*)d_out;
  float* out_rc = out_plane + 1572864;  // P*2048*3

  patch_pre2<<<768, 256, 0, stream>>>(local_fea, sw1, sb1, mw1, mb1, A1d, B1);
  point_mlp6<<<512, 512, 0, stream>>>(pos, sw1, sw2, sb2, sw3, sb3, A1d, ppd, ppf);
  neighbors_k2<<<256, 512, 0, stream>>>(ppd, nbr);
  prepack_w<<<816, 256, 0, stream>>>(mw1, mw2, mw3, cw2, W1p, W2p, W3p, C2h, C2l);
  edge_mfma<<<2048, 512, 0, stream>>>(ppf, nbr, cw1, cb1, C2h, C2l, cb2, aggB);
  final_mlp_mfma<<<1024, 256, 0, stream>>>(aggB, B1, W1p, W2p, W3p, mb2, mb3,
                                           ppf, out_plane, out_rc);
}

// Round 10
// 254.603 us; speedup vs baseline: 1.0280x; 1.0280x over previous
//
#include <hip/hip_runtime.h>

// PlanePriorNet: P=256 patches x PT=64 pts, D=768. float32 I/O.
// Round 18: consolidation. point_mlp6 = R16 form (best measured, 47.0us:
// 32 pts/block, 512 blocks, direct global weight loads - R17's LDS
// staging regressed to 53us and is reverted). final_mlp_mfma keeps R17's
// fused plane_k stage 5 (rotw buffer + launch removed). point_mlp6 is
// FROZEN: 7 structural variants (R10-R17) all pinned at >=47us; the
// bit-exact fp64 chain is at its floor. All per-element expressions
// unchanged => bit-identical outputs.

#define P 256
#define PT 64
#define NPTS 16384          // P*PT
#define M2N 32768           // 2*N
#define D 768
#define SENTK 0xFFFFFFFFFFFFFFFFull

typedef __attribute__((ext_vector_type(8))) short bfrag;   // 8 x bf16 (4 VGPR)
typedef __attribute__((ext_vector_type(4))) float ffrag;   // 4 x f32 acc

#define MFMA16(a, b, c) __builtin_amdgcn_mfma_f32_16x16x32_bf16((a), (b), (c), 0, 0, 0)

// round-to-nearest-even fp32 -> bf16
__device__ __forceinline__ ushort f2bf(float x) {
  unsigned u = __float_as_uint(x);
  u = (u + 0x7FFFu + ((u >> 16) & 1u)) >> 16;
  return (ushort)u;
}
__device__ __forceinline__ float bf2f(ushort u) {
  return __uint_as_float((unsigned)u << 16);
}

// ---------------------------------------------------------------- kernel A
// Split by column chunk: chunk 0 -> A1d (fp64, 256 cols); chunks 1,2 -> B1 (fp32).
__global__ __launch_bounds__(256) void patch_pre2(
    const float* __restrict__ lf, const float* __restrict__ sw1,
    const float* __restrict__ sb1, const float* __restrict__ mw1,
    const float* __restrict__ mb1, double* __restrict__ A1d, float* __restrict__ B1) {
  __shared__ float lfs[768];
  const int b = blockIdx.x, t = threadIdx.x;
  const int p = b / 3, chunk = b % 3;
  for (int i = t; i < 768; i += 256) lfs[i] = lf[p * 768 + i];
  __syncthreads();
  if (chunk == 0) {
    double a = (double)sb1[t];
    for (int d = 0; d < 768; ++d)
      a += (double)lfs[d] * (double)sw1[d * 256 + t];
    A1d[p * 256 + t] = a;
  } else {
    const int c = (chunk - 1) * 256 + t;
    float bb = 0.f;
    for (int d = 0; d < 768; ++d)
      bb += lfs[d] * mw1[d * 512 + c];
    B1[p * 512 + c] = mb1[c] + bb;
  }
}

// ---------------------------------------------------------------- kernel B
// Point MLP, fp64, half-patch blocks (32 pts, 512 blocks x 512 thr).
// h1T [256][34] doubles (pitch 34, 69632 B); h2s [32][129] overlays h1T.
// Stage 1: thread t -> k=t&255, rows (t>>8)*16..+16 (same per-elem expr).
// Stage 2: thread t -> col c=t&127, pt-group ptq=t>>7 (8 pts), 8 accs;
//          weight fp32 load + inline exact cvt (R11 statement form).
// FROZEN at ~47us (R10-R17: 7 structural variants all >=47us).
__global__ __launch_bounds__(512, 4) void point_mlp6(
    const float* __restrict__ pos, const float* __restrict__ sw1,
    const float* __restrict__ sw2, const float* __restrict__ sb2,
    const float* __restrict__ sw3, const float* __restrict__ sb3,
    const double* __restrict__ A1d, double* __restrict__ ppd, float* __restrict__ ppf) {
  __shared__ double smemD[8704];   // h1T [k][pt] pitch 34 (69632 B); h2s overlay
  __shared__ double posd[96];
  double* h1T = smemD;
  double* h2s = smemD;

  const int b = blockIdx.x, t = threadIdx.x;
  const int p = b >> 1, qb = b & 1;    // pts [qb*32, qb*32+32)
  if (t < 96) posd[t] = (double)pos[p * 192 + qb * 96 + t];
  __syncthreads();

  // stage 1: h1T[k][r] = relu(A1[k] + pos . sw1'[k])   (round-4 expression)
  {
    const int k = t & 255, rb = (t >> 8) * 16;
    const double a1 = A1d[p * 256 + k];
    const double w0 = (double)sw1[768 * 256 + k];
    const double w1 = (double)sw1[769 * 256 + k];
    const double w2 = (double)sw1[770 * 256 + k];
    for (int r = rb; r < rb + 16; ++r) {
      const double* pp = &posd[r * 3];
      const double v = a1 + pp[0] * w0 + pp[1] * w1 + pp[2] * w2;
      h1T[k * 34 + r] = v > 0.0 ? v : 0.0;
    }
  }
  __syncthreads();

  // stage 2: h2[pt][c] = relu(sb2 + sum_k h1[pt][k]*sw2[k][c])
  // (per-acc k-chain sequential 0..255, identical statement form => bit-identical)
  {
    const int c = t & 127, ptq = t >> 7;   // pts ptq*8 .. ptq*8+7
    double acc[8];
    #pragma unroll
    for (int i = 0; i < 8; ++i) acc[i] = 0.0;
    const float* wp = sw2 + c;               // wp[k*128]
    const double* hp = h1T + ptq * 8;        // hp[k*34 + i], 16B-aligned
    #pragma unroll 4
    for (int k = 0; k < 256; ++k) {
      const double2 h01 = *(const double2*)&hp[k * 34];
      const double2 h23 = *(const double2*)&hp[k * 34 + 2];
      const double2 h45 = *(const double2*)&hp[k * 34 + 4];
      const double2 h67 = *(const double2*)&hp[k * 34 + 6];
      const double w = (double)wp[k * 128];
      acc[0] += h01.x * w;
      acc[1] += h01.y * w;
      acc[2] += h23.x * w;
      acc[3] += h23.y * w;
      acc[4] += h45.x * w;
      acc[5] += h45.y * w;
      acc[6] += h67.x * w;
      acc[7] += h67.y * w;
    }
    __syncthreads();  // all h1T reads done; overlay h2s
    #pragma unroll
    for (int i = 0; i < 8; ++i) {
      const int pt = ptq * 8 + i;
      const double u = acc[i] + (double)sb2[c];
      h2s[pt * 129 + c] = u > 0.0 ? u : 0.0;
    }
  }
  __syncthreads();

  // stage 3: h3 + tanh + writes (96 threads; round-4 sequential c-sum)
  if (t < 96) {
    const int r = t / 3, j = t % 3;
    double u = (double)sb3[j];
    #pragma unroll 4
    for (int c = 0; c < 128; ++c)
      u += h2s[r * 129 + c] * (double)sw3[c * 3 + j];
    u = u > 0.0 ? u : 0.0;
    const int s = qb * 32 + r;
    const double po = posd[r * 3 + j];
    const double np_ = tanh(u) + po;
    const size_t rn = (size_t)(p * 128 + 64 + s) * 3 + j;
    const size_t ro = (size_t)(p * 128 + s) * 3 + j;
    ppd[rn] = np_;  ppf[rn] = (float)np_;
    ppd[ro] = po;   ppf[ro] = (float)po;
  }
}

// ---------------------------------------------------------------- kernel C
// Top-9 via u64 keys: key=(bits(d2)&~127)|j; branch-free sorted-insert;
// 4 segments x 32 candidates per row; tree merge via LDS (9+9 inserts).
__device__ __forceinline__ void ins9(unsigned long long* s, unsigned long long key) {
  #pragma unroll
  for (int k = 8; k >= 1; --k) {
    const unsigned long long lo = s[k - 1];
    const unsigned long long mx = key > lo ? key : lo;
    s[k] = (key >= s[k]) ? s[k] : mx;
  }
  s[0] = key < s[0] ? key : s[0];
}

__global__ __launch_bounds__(512) void neighbors_k2(const double* __restrict__ ppd,
                                                    int* __restrict__ nbr) {
  __shared__ double PX[128], PY[128], PZ[128];
  __shared__ unsigned long long mbuf[2][128][9];   // 18432 B
  const int p = blockIdx.x, t = threadIdx.x;
  const int row = t & 127, seg = t >> 7;
  if (t < 128) {
    PX[t] = ppd[(p * 128 + t) * 3 + 0];
    PY[t] = ppd[(p * 128 + t) * 3 + 1];
    PZ[t] = ppd[(p * 128 + t) * 3 + 2];
  }
  __syncthreads();
  const double R2d = 0.3 * 0.3;
  const double xi = PX[row], yi = PY[row], zi = PZ[row];
  unsigned long long s[9];
  #pragma unroll
  for (int k = 0; k < 9; ++k) s[k] = SENTK;
  const int j0 = seg * 32;
  for (int jj = 0; jj < 32; ++jj) {
    const int j = j0 + jj;
    const double dx = PX[j] - xi, dy = PY[j] - yi, dz = PZ[j] - zi;
    const double d2 = dx * dx + dy * dy + dz * dz;
    unsigned long long key =
        (((unsigned long long)__double_as_longlong(d2)) & ~127ull) | (unsigned long long)j;
    key = (d2 <= R2d) ? key : SENTK;
    ins9(s, key);
  }
  if (seg & 1) {
    #pragma unroll
    for (int k = 0; k < 9; ++k) mbuf[seg >> 1][row][k] = s[k];
  }
  __syncthreads();
  if (!(seg & 1)) {
    #pragma unroll
    for (int m = 0; m < 9; ++m) ins9(s, mbuf[seg >> 1][row][m]);
  }
  if (seg == 2) {
    #pragma unroll
    for (int k = 0; k < 9; ++k) mbuf[1][row][k] = s[k];
  }
  __syncthreads();
  if (seg == 0) {
    #pragma unroll
    for (int m = 0; m < 9; ++m) ins9(s, mbuf[1][row][m]);
    #pragma unroll
    for (int k = 0; k < 9; ++k)
      nbr[(p * 128 + row) * 9 + k] = (s[k] == SENTK) ? -1 : (int)(s[k] & 127);
  }
}

// ---------------------------------------------------------------- kernel W
// Pack mw1[768:896], mw2, mw3(pad N->16), cw2(hi/lo) into MFMA B-fragment order:
// dst[((nt*KT + kt)*64 + lane)*8 + j] = W[kt*32 + (lane>>4)*8 + j][nt*16 + (lane&15)]
__global__ __launch_bounds__(256) void prepack_w(
    const float* __restrict__ mw1, const float* __restrict__ mw2,
    const float* __restrict__ mw3, const float* __restrict__ cw2,
    ushort* __restrict__ W1p, ushort* __restrict__ W2p, ushort* __restrict__ W3p,
    ushort* __restrict__ C2h, ushort* __restrict__ C2l) {
  const int idx = blockIdx.x * 256 + threadIdx.x;
  if (idx < 65536) {                       // W1p: K=128 (kt<4), N=512 (nt<32)
    const int j = idx & 7, l = (idx >> 3) & 63, kt = (idx >> 9) & 3, nt = idx >> 11;
    const int k = kt * 32 + (l >> 4) * 8 + j, n = nt * 16 + (l & 15);
    W1p[idx] = f2bf(mw1[(768 + k) * 512 + n]);
  } else if (idx < 196608) {               // W2p: K=512 (kt<16), N=256 (nt<16)
    const int q = idx - 65536;
    const int j = q & 7, l = (q >> 3) & 63, kt = (q >> 9) & 15, nt = q >> 13;
    const int k = kt * 32 + (l >> 4) * 8 + j, n = nt * 16 + (l & 15);
    W2p[q] = f2bf(mw2[k * 256 + n]);
  } else if (idx < 200704) {               // W3p: K=256 (kt<8), N=9 padded to 16
    const int q = idx - 196608;
    const int j = q & 7, l = (q >> 3) & 63, kt = q >> 9;
    const int k = kt * 32 + (l >> 4) * 8 + j, n = l & 15;
    W3p[q] = (n < 9) ? f2bf(mw3[k * 9 + n]) : (ushort)0;
  } else if (idx < 208896) {               // C2h/C2l: K=64 (kt<2), N=128 (nt<8)
    const int q = idx - 200704;
    const int j = q & 7, l = (q >> 3) & 63, kt = (q >> 9) & 1, nt = q >> 10;
    const int k = kt * 32 + (l >> 4) * 8 + j, n = nt * 16 + (l & 15);
    const float v = cw2[k * 128 + n];
    const ushort hi = f2bf(v);
    C2h[q] = hi;
    C2l[q] = f2bf(v - bf2f(hi));
  }
}

// ---------------------------------------------------------------- kernel D
// Edge MLP via MFMA: 16 pts/block (144 edges, M-tiles=9), N=128, K=64.
// 512 threads (8 waves); wave w owns the single 16-col N-tile nt=w.
#define EPITCH 80    // m1 pitch (ushorts): 160 B rows
#define M2PITCH 132  // m2 pitch (ushorts): 264 B rows
__global__ __launch_bounds__(512, 6) void edge_mfma(
    const float* __restrict__ ppf, const int* __restrict__ nbr,
    const float* __restrict__ cw1, const float* __restrict__ cb1,
    const ushort* __restrict__ C2h, const ushort* __restrict__ C2l,
    const float* __restrict__ cb2, ushort* __restrict__ aggB) {
  __shared__ float posL[128 * 3];
  __shared__ int nbrL[144];
  __shared__ __align__(16) ushort buf[2 * 144 * EPITCH];  // m1h|m1l, reused as m2
  ushort* m1h = buf;
  ushort* m1l = buf + 144 * EPITCH;
  ushort* m2L = buf;   // 144*132 = 19008 <= 23040

  const int b = blockIdx.x, t = threadIdx.x;
  const int p = b >> 3, off = (b & 7) * 16;
  for (int i = t; i < 384; i += 512) posL[i] = ppf[p * 384 + i];
  if (t < 144) nbrL[t] = nbr[(p * 128 + off) * 9 + t];
  __syncthreads();

  // phase 1: m1[e][c] = relu(feat . cw1[:,c] + cb1[c]) -> bf16 hi/lo
  // thread t -> channel pair (c0,c0+1), edge group eg (9 edges each)
  {
    const int c0 = (t & 31) * 2, eg = t >> 5;
    float w1a[6], w1b[6];
    #pragma unroll
    for (int q = 0; q < 6; ++q) {
      w1a[q] = cw1[q * 64 + c0];
      w1b[q] = cw1[q * 64 + c0 + 1];
    }
    const float b1a = cb1[c0], b1b = cb1[c0 + 1];
    for (int e = eg; e < 144; e += 16) {
      const int pl = e / 9;
      const int j = nbrL[e];
      const int jj = j < 0 ? 0 : j;
      const int ctr = off + pl;
      const float nx = posL[jj * 3], ny = posL[jj * 3 + 1], nz = posL[jj * 3 + 2];
      const float cx = posL[ctr * 3], cy = posL[ctr * 3 + 1], cz = posL[ctr * 3 + 2];
      float va = b1a + nx * w1a[0] + ny * w1a[1] + nz * w1a[2] +
                 (nx - cx) * w1a[3] + (ny - cy) * w1a[4] + (nz - cz) * w1a[5];
      va = fmaxf(va, 0.f);
      float vb = b1b + nx * w1b[0] + ny * w1b[1] + nz * w1b[2] +
                 (nx - cx) * w1b[3] + (ny - cy) * w1b[4] + (nz - cz) * w1b[5];
      vb = fmaxf(vb, 0.f);
      const ushort hia = f2bf(va), hib = f2bf(vb);
      const ushort loa = f2bf(va - bf2f(hia)), lob = f2bf(vb - bf2f(hib));
      *(unsigned*)&m1h[e * EPITCH + c0] = (unsigned)hia | ((unsigned)hib << 16);
      *(unsigned*)&m1l[e * EPITCH + c0] = (unsigned)loa | ((unsigned)lob << 16);
    }
  }
  __syncthreads();

  // phase 2: MFMA, wave w covers cols [w*16, w*16+16)
  const int w = t >> 6, l = t & 63, lrow = l & 15, quad = l >> 4;
  ffrag acc[9];
  {
    bfrag Bh[2], Bl[2];  // [kt]
    #pragma unroll
    for (int kt = 0; kt < 2; ++kt) {
      const int bi = ((w * 2 + kt) * 64 + l) * 8;
      Bh[kt] = *(const bfrag*)&C2h[bi];
      Bl[kt] = *(const bfrag*)&C2l[bi];
    }
    #pragma unroll
    for (int mt = 0; mt < 9; ++mt) {
      bfrag Ah[2], Al[2];
      #pragma unroll
      for (int kt = 0; kt < 2; ++kt) {
        const int ai = (mt * 16 + lrow) * EPITCH + kt * 32 + quad * 8;
        Ah[kt] = *(const bfrag*)&m1h[ai];
        Al[kt] = *(const bfrag*)&m1l[ai];
      }
      ffrag a = (ffrag){0.f, 0.f, 0.f, 0.f};
      #pragma unroll
      for (int kt = 0; kt < 2; ++kt) {
        a = MFMA16(Ah[kt], Bh[kt], a);
        a = MFMA16(Ah[kt], Bl[kt], a);
        a = MFMA16(Al[kt], Bh[kt], a);
      }
      acc[mt] = a;
    }
  }
  __syncthreads();  // all m1 reads done; buf reusable

  // phase 3: epilogue bias+relu -> bf16 -> m2L
  {
    const float cbv = cb2[w * 16 + lrow];
    const int col = w * 16 + lrow;
    #pragma unroll
    for (int mt = 0; mt < 9; ++mt) {
      #pragma unroll
      for (int r = 0; r < 4; ++r) {
        const int row = mt * 16 + quad * 4 + r;
        m2L[row * M2PITCH + col] = f2bf(fmaxf(acc[mt][r] + cbv, 0.f));
      }
    }
  }
  __syncthreads();

  // phase 4: max over valid neighbors, channel pairs via b32 reads
  // (ushort compare valid: all values >= 0)
  for (int o = t; o < 1024; o += 512) {
    const int pt = o >> 6, cc = (o & 63) * 2;
    ushort b0 = 0, b1 = 0;
    #pragma unroll
    for (int s = 0; s < 9; ++s) {
      if (nbrL[pt * 9 + s] >= 0) {
        const unsigned u = *(const unsigned*)&m2L[(pt * 9 + s) * M2PITCH + cc];
        const ushort u0 = (ushort)u, u1 = (ushort)(u >> 16);
        b0 = u0 > b0 ? u0 : b0;
        b1 = u1 > b1 ? u1 : b1;
      }
    }
    *(unsigned*)&aggB[(size_t)(p * 128 + off + pt) * 128 + cc] =
        (unsigned)b0 | ((unsigned)b1 << 16);
  }
}

// ---------------------------------------------------------------- kernel E
// Final MLP via MFMA: 32 rows/block, 1024 blocks. agg bf16.
// Stage 5 (fused plane_k): plane outputs for this block's 32 rot rows.
#define PA  136   // aT pitch (bf16 elems)
#define PG1 520
#define PG2 264
__global__ __launch_bounds__(256) void final_mlp_mfma(
    const ushort* __restrict__ aggB, const float* __restrict__ B1,
    const ushort* __restrict__ W1p, const ushort* __restrict__ W2p,
    const ushort* __restrict__ W3p, const float* __restrict__ mb2,
    const float* __restrict__ mb3, const float* __restrict__ ppf,
    float* __restrict__ out_plane, float* __restrict__ out_rc) {
  __shared__ __align__(16) ushort g1T[32 * PG1];   // 33280 B
  __shared__ __align__(16) ushort reg2[32 * PG2];  // 16896 B: aT then g2T
  __shared__ float rotL[32 * 9];
  const int b = blockIdx.x, t = threadIdx.x;
  const int w = t >> 6, l = t & 63;
  const int lrow = l & 15, quad = l >> 4;
  int p, off;
  if (b < 512) { p = b >> 1;         off = (b & 1) * 32; }
  else         { p = (b - 512) >> 1; off = 64 + ((b - 512) & 1) * 32; }
  const int n0 = b * 32;

  // ---- stage 0: aggB tile (bf16) -> LDS aT[32][128] pitch PA
  {
    ushort* aT = reg2;
    const int r0 = t >> 3, sg = (t & 7) * 16;
    const ushort* src = aggB + (size_t)(p * 128 + off + r0) * 128 + sg;
    const uint4 v0 = *(const uint4*)src;
    const uint4 v1 = *(const uint4*)(src + 8);
    *(uint4*)&aT[r0 * PA + sg] = v0;
    *(uint4*)&aT[r0 * PA + sg + 8] = v1;
  }
  __syncthreads();

  // ---- stage 1: g1 (M=32, N=512, K=128); wave w: N cols [w*128, w*128+128)
  {
    const ushort* aT = reg2;
    bfrag a[2][4];
    #pragma unroll
    for (int mt = 0; mt < 2; ++mt)
      #pragma unroll
      for (int kt = 0; kt < 4; ++kt)
        a[mt][kt] = *(const bfrag*)&aT[(mt * 16 + lrow) * PA + kt * 32 + quad * 8];
    ffrag acc[2][8];
    #pragma unroll
    for (int nti = 0; nti < 8; ++nti) {
      const float bv = B1[p * 512 + (w * 8 + nti) * 16 + lrow];
      acc[0][nti] = (ffrag){bv, bv, bv, bv};
      acc[1][nti] = acc[0][nti];
    }
    #pragma unroll
    for (int nti = 0; nti < 8; ++nti) {
      const int nt = w * 8 + nti;
      #pragma unroll
      for (int kt = 0; kt < 4; ++kt) {
        const bfrag bb = *(const bfrag*)&W1p[((nt * 4 + kt) * 64 + l) * 8];
        acc[0][nti] = MFMA16(a[0][kt], bb, acc[0][nti]);
        acc[1][nti] = MFMA16(a[1][kt], bb, acc[1][nti]);
      }
    }
    #pragma unroll
    for (int mt = 0; mt < 2; ++mt)
      #pragma unroll
      for (int nti = 0; nti < 8; ++nti) {
        const int col = (w * 8 + nti) * 16 + lrow;
        #pragma unroll
        for (int r = 0; r < 4; ++r)
          g1T[(mt * 16 + quad * 4 + r) * PG1 + col] = f2bf(fmaxf(acc[mt][nti][r], 0.f));
      }
  }
  __syncthreads();

  // ---- stage 2: g2 (M=32, N=256, K=512); wave w: N cols [w*64, w*64+64)
  {
    bfrag a[2][16];
    #pragma unroll
    for (int mt = 0; mt < 2; ++mt)
      #pragma unroll
      for (int kt = 0; kt < 16; ++kt)
        a[mt][kt] = *(const bfrag*)&g1T[(mt * 16 + lrow) * PG1 + kt * 32 + quad * 8];
    ffrag acc[2][4];
    #pragma unroll
    for (int nti = 0; nti < 4; ++nti) {
      acc[0][nti] = (ffrag){0.f, 0.f, 0.f, 0.f};
      acc[1][nti] = acc[0][nti];
    }
    #pragma unroll
    for (int nti = 0; nti < 4; ++nti) {
      const int nt = w * 4 + nti;
      #pragma unroll
      for (int kt = 0; kt < 16; ++kt) {
        const bfrag bb = *(const bfrag*)&W2p[((nt * 16 + kt) * 64 + l) * 8];
        acc[0][nti] = MFMA16(a[0][kt], bb, acc[0][nti]);
        acc[1][nti] = MFMA16(a[1][kt], bb, acc[1][nti]);
      }
    }
    ushort* g2T = reg2;
    #pragma unroll
    for (int mt = 0; mt < 2; ++mt)
      #pragma unroll
      for (int nti = 0; nti < 4; ++nti) {
        const int col = (w * 4 + nti) * 16 + lrow;
        const float bv = mb2[col];
        #pragma unroll
        for (int r = 0; r < 4; ++r)
          g2T[(mt * 16 + quad * 4 + r) * PG2 + col] =
              f2bf(fmaxf(acc[mt][nti][r] + bv, 0.f));
      }
  }
  __syncthreads();

  // ---- stage 3: g3 (M=32, N=16 padded, K=256); waves 0,1 take mt=w
  if (w < 2) {
    const ushort* g2T = reg2;
    ffrag acc = (ffrag){0.f, 0.f, 0.f, 0.f};
    #pragma unroll
    for (int kt = 0; kt < 8; ++kt) {
      const bfrag aa = *(const bfrag*)&g2T[(w * 16 + lrow) * PG2 + kt * 32 + quad * 8];
      const bfrag bb = *(const bfrag*)&W3p[(kt * 64 + l) * 8];
      acc = MFMA16(aa, bb, acc);
    }
    if (lrow < 9) {
      const float bv = mb3[lrow];
      #pragma unroll
      for (int r = 0; r < 4; ++r) {
        const int m = w * 16 + quad * 4 + r;
        rotL[m * 9 + lrow] = fmaxf(acc[r] + bv, 0.f);
      }
    }
  }
  __syncthreads();

  // ---- stage 4: rot_constrain
  for (int idx = t; idx < 288; idx += 256) {
    const int r = idx / 9, e = idx % 9, ii = e / 3, jj = e % 3;
    const float* R = &rotL[r * 9];
    out_rc[(size_t)(n0 + r) * 9 + e] =
        R[ii] * R[jj] + R[3 + ii] * R[3 + jj] + R[6 + ii] * R[6 + jj];
  }

  // ---- stage 5: plane outputs for q in [n0*16, n0*16+512)  (fused plane_k)
  for (int ii = t; ii < 512; ii += 256) {
    const int q = n0 * 16 + ii;
    const int n_loc = ii >> 4, tt = ii & 15;
    const float* R = &rotL[n_loc * 9];
    const int tx = tt & 3, ty = tt >> 2;
    const double step = 0.4 / 3.0;
    const float X = (tx == 3) ? 0.2f : (float)((double)tx * step - 0.2);
    const float Y = (ty == 3) ? 0.2f : (float)((double)ty * step - 0.2);
    const int m = q & (M2N - 1);
    int pp, s;
    if (m < NPTS) { pp = m >> 6; s = m & 63; }
    else          { const int mm = m - NPTS; pp = mm >> 6; s = 64 + (mm & 63); }
    const float* C = &ppf[(pp * 128 + s) * 3];
    #pragma unroll
    for (int i2 = 0; i2 < 3; ++i2) {
      const float d = R[i2 * 3 + 0] * X + R[i2 * 3 + 1] * Y;  // npts z == 0
      out_plane[(size_t)q * 3 + i2] = d + C[i2];
    }
  }
}

// ---------------------------------------------------------------- launch
extern "C" void kernel_launch(void* const* d_in, const int* in_sizes, int n_in,
                              void* d_out, int out_size, void* d_ws, size_t ws_size,
                              hipStream_t stream) {
  const float* pos       = (const float*)d_in[1];
  const float* local_fea = (const float*)d_in[4];
  const float* sw1 = (const float*)d_in[5];
  const float* sb1 = (const float*)d_in[6];
  const float* sw2 = (const float*)d_in[7];
  const float* sb2 = (const float*)d_in[8];
  const float* sw3 = (const float*)d_in[9];
  const float* sb3 = (const float*)d_in[10];
  const float* cw1 = (const float*)d_in[11];
  const float* cb1 = (const float*)d_in[12];
  const float* cw2 = (const float*)d_in[13];
  const float* cb2 = (const float*)d_in[14];
  const float* mw1 = (const float*)d_in[15];
  const float* mb1 = (const float*)d_in[16];
  const float* mw2 = (const float*)d_in[17];
  const float* mb2 = (const float*)d_in[18];
  const float* mw3 = (const float*)d_in[19];
  const float* mb3 = (const float*)d_in[20];

  char* ws = (char*)d_ws;
  double* A1d  = (double*)(ws + 0);         // 524288
  double* ppd  = (double*)(ws + 524288);    // 786432
  float*  B1   = (float*)(ws + 1310720);    // 524288
  float*  ppf  = (float*)(ws + 1835008);    // 393216
  int*    nbr  = (int*)(ws + 2228224);      // 1179648
  ushort* aggB = (ushort*)(ws + 3407872);   // 8388608
  ushort* W1p  = (ushort*)(ws + 12976128);  // 131072
  ushort* W2p  = (ushort*)(ws + 13107200);  // 262144
  ushort* W3p  = (ushort*)(ws + 13369344);  // 8192
  ushort* C2h  = (ushort*)(ws + 13377536);  // 16384
  ushort* C2l  = (ushort*)(ws + 13393920);  // 16384 (end 13410304)

  float* out_plane = (float*)d_out;
  float* out_rc = out_plane + 1572864;  // P*2048*3

  patch_pre2<<<768, 256, 0, stream>>>(local_fea, sw1, sb1, mw1, mb1, A1d, B1);
  point_mlp6<<<512, 512, 0, stream>>>(pos, sw1, sw2, sb2, sw3, sb3, A1d, ppd, ppf);
  neighbors_k2<<<256, 512, 0, stream>>>(ppd, nbr);
  prepack_w<<<816, 256, 0, stream>>>(mw1, mw2, mw3, cw2, W1p, W2p, W3p, C2h, C2l);
  edge_mfma<<<2048, 512, 0, stream>>>(ppf, nbr, cw1, cb1, C2h, C2l, cb2, aggB);
  final_mlp_mfma<<<1024, 256, 0, stream>>>(aggB, B1, W1p, W2p, W3p, mb2, mb3,
                                           ppf, out_plane, out_rc);
}